// Round 1
// baseline (115.177 us; speedup 1.0000x reference)
//
#include <hip/hip_runtime.h>
#include <math.h>

namespace {

constexpr int   HW     = 128;
constexpr int   HWHW   = HW * HW;
constexpr float NEAR_P = 0.2f;
constexpr float EPS_P  = 1e-8f;
constexpr int   REC    = 16;     // floats per triangle record (float4-aligned)
constexpr int   SORT_N = 1024;   // pow2 >= N
constexpr int   CHUNK  = 128;    // triangles staged in LDS per pass

__device__ inline void project_vertex(const float* __restrict__ vm,
                                      const float* __restrict__ pm,
                                      float x, float y, float z,
                                      float& px, float& py, float& zv)
{
    // row-vector [x,y,z,1] @ M (row-major 4x4)
    zv = x * vm[2] + y * vm[6] + z * vm[10] + vm[14];
    float h0 = x * pm[0] + y * pm[4] + z * pm[8]  + pm[12];
    float h1 = x * pm[1] + y * pm[5] + z * pm[9]  + pm[13];
    float h3 = x * pm[3] + y * pm[7] + z * pm[11] + pm[15];
    float w  = h3 + 1e-7f;
    float n0 = h0 / w;
    float n1 = h1 / w;
    px = ((n0 + 1.0f) * (float)HW - 1.0f) * 0.5f;
    py = ((n1 + 1.0f) * (float)HW - 1.0f) * 0.5f;
}

// One block. Projects, computes radii, sorts by (depth, idx) via bitonic in
// LDS, writes depth-sorted per-triangle records to d_ws.
__global__ __launch_bounds__(SORT_N)
void prep_sort_kernel(const float* __restrict__ vertex,   // N*9
                      const float* __restrict__ opacity,  // N
                      const float* __restrict__ feature,  // N*3
                      const float* __restrict__ vm,       // 16
                      const float* __restrict__ pm,       // 16
                      float* __restrict__ recs,           // SORT_N*REC
                      float* __restrict__ radii,          // N (float values)
                      int N)
{
    __shared__ float s_d[SORT_N];
    __shared__ int   s_i[SORT_N];
    const int t = threadIdx.x;

    if (t < N) {
        const float* v = vertex + t * 9;
        float px[3], py[3], zv[3];
        #pragma unroll
        for (int k = 0; k < 3; ++k)
            project_vertex(vm, pm, v[k*3+0], v[k*3+1], v[k*3+2], px[k], py[k], zv[k]);
        float area = (px[1]-px[0])*(py[2]-py[0]) - (py[1]-py[0])*(px[2]-px[0]);
        bool  valid = (fabsf(area) > EPS_P) &&
                      (fminf(zv[0], fminf(zv[1], zv[2])) > NEAR_P);
        float cx = (px[0] + px[1] + px[2]) / 3.0f;
        float cy = (py[0] + py[1] + py[2]) / 3.0f;
        float r = 0.0f;
        #pragma unroll
        for (int k = 0; k < 3; ++k) {
            float dx = px[k] - cx, dy = py[k] - cy;
            r = fmaxf(r, sqrtf(dx*dx + dy*dy));
        }
        radii[t] = valid ? ceilf(r) : 0.0f;
        s_d[t] = (zv[0] + zv[1] + zv[2]) / 3.0f;
    } else {
        s_d[t] = INFINITY;
    }
    s_i[t] = t;
    __syncthreads();

    // bitonic sort ascending by (depth, idx) — idx tiebreak == stable argsort
    for (int k = 2; k <= SORT_N; k <<= 1) {
        for (int j = k >> 1; j > 0; j >>= 1) {
            int ixj = t ^ j;
            if (ixj > t) {
                float d0 = s_d[t], d1 = s_d[ixj];
                int   i0 = s_i[t], i1 = s_i[ixj];
                bool gt = (d0 > d1) || (d0 == d1 && i0 > i1);
                bool up = ((t & k) == 0);
                if (gt == up) {
                    s_d[t] = d1; s_d[ixj] = d0;
                    s_i[t] = i1; s_i[ixj] = i0;
                }
            }
            __syncthreads();
        }
    }

    // gather: thread t owns sorted slot t, recomputes record of triangle src
    if (t < N) {
        int src = s_i[t];
        const float* v = vertex + src * 9;
        float px[3], py[3], zv[3];
        #pragma unroll
        for (int k = 0; k < 3; ++k)
            project_vertex(vm, pm, v[k*3+0], v[k*3+1], v[k*3+2], px[k], py[k], zv[k]);
        float ax = px[0], ay = py[0];
        float bx = px[1], by = py[1];
        float cx = px[2], cy = py[2];
        float area = (bx-ax)*(cy-ay) - (by-ay)*(cx-ax);
        bool  okA  = fabsf(area) > EPS_P;
        bool  valid = okA && (fminf(zv[0], fminf(zv[1], zv[2])) > NEAR_P);
        float inv = okA ? 1.0f / area : 0.0f;
        float* R = recs + t * REC;
        // w0 = edge(b,c)*inv : (X-bx)*(cy-by) - (Y-by)*(cx-bx)
        R[0] = (cy - by) * inv;
        R[1] = -(cx - bx) * inv;
        R[2] = (by * (cx - bx) - bx * (cy - by)) * inv;
        // w1 = edge(c,a)*inv
        R[3] = (ay - cy) * inv;
        R[4] = -(ax - cx) * inv;
        R[5] = (cy * (ax - cx) - cx * (ay - cy)) * inv;
        // w2 = edge(a,b)*inv
        R[6] = (by - ay) * inv;
        R[7] = -(bx - ax) * inv;
        R[8] = (ay * (bx - ax) - ax * (by - ay)) * inv;
        R[9]  = valid ? opacity[src] : 0.0f;   // effective opacity
        R[10] = feature[src*3 + 0];
        R[11] = feature[src*3 + 1];
        R[12] = feature[src*3 + 2];
        R[13] = 0.0f; R[14] = 0.0f; R[15] = 0.0f;
    }
}

// 64 blocks x 256 threads: one pixel per thread, 16x16 tile per block.
// Walk sorted triangles front-to-back, composite.
__global__ __launch_bounds__(256)
void composite_kernel(const float* __restrict__ recs, int N,
                      const float* __restrict__ background,
                      float* __restrict__ out)
{
    __shared__ float s_chunk[CHUNK * REC];
    const int tid = threadIdx.x;
    const int pxi = ((int)blockIdx.x & 7) * 16 + (tid & 15);
    const int pyi = ((int)blockIdx.x >> 3) * 16 + (tid >> 4);
    const float X = (float)pxi + 0.5f;
    const float Y = (float)pyi + 0.5f;

    float T = 1.0f, cr = 0.0f, cg = 0.0f, cb = 0.0f;

    for (int base = 0; base < N; base += CHUNK) {
        int cnt = min(CHUNK, N - base);
        __syncthreads();
        const float4* src = (const float4*)(recs + base * REC);
        float4*       dst = (float4*)s_chunk;
        for (int k = tid; k < cnt * (REC / 4); k += 256) dst[k] = src[k];
        __syncthreads();

        for (int j = 0; j < cnt; ++j) {
            const float* R = &s_chunk[j * REC];
            float w0 = fmaf(R[0], X, fmaf(R[1], Y, R[2]));
            float w1 = fmaf(R[3], X, fmaf(R[4], Y, R[5]));
            float w2 = fmaf(R[6], X, fmaf(R[7], Y, R[8]));
            float mn = fminf(w0, fminf(w1, w2));
            float cov = fminf(fmaxf(3.0f * mn, 0.0f), 1.0f);
            if (cov > 0.0f) {
                float alpha = fminf(R[9] * cov, 0.999f);
                float w = T * alpha;
                cr = fmaf(w, R[10], cr);
                cg = fmaf(w, R[11], cg);
                cb = fmaf(w, R[12], cb);
                T *= (1.0f - alpha);
            }
        }
    }

    const int pix = pyi * HW + pxi;
    out[pix]            = fmaf(T, background[0], cr);
    out[HWHW + pix]     = fmaf(T, background[1], cg);
    out[2 * HWHW + pix] = fmaf(T, background[2], cb);
}

} // namespace

extern "C" void kernel_launch(void* const* d_in, const int* in_sizes, int n_in,
                              void* d_out, int out_size, void* d_ws, size_t ws_size,
                              hipStream_t stream)
{
    const float* vertex   = (const float*)d_in[0];
    // d_in[1] = center2D (unused by reference output)
    const float* opacity  = (const float*)d_in[2];
    const float* feature  = (const float*)d_in[3];
    const float* vm       = (const float*)d_in[4];
    const float* pm       = (const float*)d_in[5];
    // d_in[6] = campos (unused)
    const float* bg       = (const float*)d_in[7];

    const int N = in_sizes[0] / 9;   // 1024

    float* out   = (float*)d_out;            // [3*128*128] feature, then [N] radii
    float* recs  = (float*)d_ws;             // SORT_N * REC floats

    prep_sort_kernel<<<1, SORT_N, 0, stream>>>(vertex, opacity, feature, vm, pm,
                                               recs, out + 3 * HWHW, N);
    composite_kernel<<<64, 256, 0, stream>>>(recs, N, bg, out);
}

// Round 2
// 42.218 us; speedup vs baseline: 2.7282x; 2.7282x over previous
//
#include <hip/hip_runtime.h>
#include <math.h>

namespace {

constexpr int   HW     = 128;
constexpr int   HWHW   = HW * HW;
constexpr float NEAR_P = 0.2f;
constexpr float EPS_P  = 1e-8f;
constexpr int   REC    = 16;     // floats per triangle record (float4-aligned)
constexpr int   SORT_N = 1024;   // pow2 >= N

__device__ inline void project_vertex(const float* __restrict__ vm,
                                      const float* __restrict__ pm,
                                      float x, float y, float z,
                                      float& px, float& py, float& zv)
{
    // row-vector [x,y,z,1] @ M (row-major 4x4)
    zv = x * vm[2] + y * vm[6] + z * vm[10] + vm[14];
    float h0 = x * pm[0] + y * pm[4] + z * pm[8]  + pm[12];
    float h1 = x * pm[1] + y * pm[5] + z * pm[9]  + pm[13];
    float h3 = x * pm[3] + y * pm[7] + z * pm[11] + pm[15];
    float w  = h3 + 1e-7f;
    float n0 = h0 / w;
    float n1 = h1 / w;
    px = ((n0 + 1.0f) * (float)HW - 1.0f) * 0.5f;
    py = ((n1 + 1.0f) * (float)HW - 1.0f) * 0.5f;
}

// One block of 1024 threads. Projects, computes radii, sorts (depth, idx) by
// register/shfl bitonic (LDS only for j>=64 stages), writes depth-sorted
// per-triangle records + screen bboxes to d_ws.
__global__ __launch_bounds__(SORT_N)
void prep_sort_kernel(const float* __restrict__ vertex,   // N*9
                      const float* __restrict__ opacity,  // N
                      const float* __restrict__ feature,  // N*3
                      const float* __restrict__ vm,       // 16
                      const float* __restrict__ pm,       // 16
                      float* __restrict__ recs,           // SORT_N*REC
                      float4* __restrict__ bbox,          // SORT_N
                      float* __restrict__ radii,          // N (float values)
                      int N)
{
    __shared__ float s_d[SORT_N];
    __shared__ int   s_i[SORT_N];
    const int t = threadIdx.x;

    float d = INFINITY;
    if (t < N) {
        const float* v = vertex + t * 9;
        float px[3], py[3], zv[3];
        #pragma unroll
        for (int k = 0; k < 3; ++k)
            project_vertex(vm, pm, v[k*3+0], v[k*3+1], v[k*3+2], px[k], py[k], zv[k]);
        float area = (px[1]-px[0])*(py[2]-py[0]) - (py[1]-py[0])*(px[2]-px[0]);
        bool  valid = (fabsf(area) > EPS_P) &&
                      (fminf(zv[0], fminf(zv[1], zv[2])) > NEAR_P);
        float cx = (px[0] + px[1] + px[2]) / 3.0f;
        float cy = (py[0] + py[1] + py[2]) / 3.0f;
        float r = 0.0f;
        #pragma unroll
        for (int k = 0; k < 3; ++k) {
            float dx = px[k] - cx, dy = py[k] - cy;
            r = fmaxf(r, sqrtf(dx*dx + dy*dy));
        }
        radii[t] = valid ? ceilf(r) : 0.0f;
        d = (zv[0] + zv[1] + zv[2]) / 3.0f;
    }
    int idx = t;

    // bitonic sort ascending by (d, idx); keys in registers.
    // j < 64: intra-wave shfl_xor (no barrier). j >= 64: LDS exchange.
    for (int k = 2; k <= SORT_N; k <<= 1) {
        for (int j = k >> 1; j > 0; j >>= 1) {
            float pd; int pidx;
            if (j < 64) {
                pd   = __shfl_xor(d, j);
                pidx = __shfl_xor(idx, j);
            } else {
                __syncthreads();
                s_d[t] = d; s_i[t] = idx;
                __syncthreads();
                pd = s_d[t ^ j]; pidx = s_i[t ^ j];
            }
            bool asc    = ((t & k) == 0);
            bool iLower = ((t & j) == 0);
            bool mygt = (d > pd) || (d == pd && idx > pidx);
            bool mylt = (d < pd) || (d == pd && idx < pidx);
            bool take = asc ? (iLower ? mygt : mylt) : (iLower ? mylt : mygt);
            if (take) { d = pd; idx = pidx; }
        }
    }

    // thread t now owns sorted rank t -> triangle `idx`. Recompute + write.
    if (t < N) {
        int src = idx;
        const float* v = vertex + src * 9;
        float px[3], py[3], zv[3];
        #pragma unroll
        for (int k = 0; k < 3; ++k)
            project_vertex(vm, pm, v[k*3+0], v[k*3+1], v[k*3+2], px[k], py[k], zv[k]);
        float ax = px[0], ay = py[0];
        float bx = px[1], by = py[1];
        float cx = px[2], cy = py[2];
        float area = (bx-ax)*(cy-ay) - (by-ay)*(cx-ax);
        bool  okA  = fabsf(area) > EPS_P;
        bool  valid = okA && (fminf(zv[0], fminf(zv[1], zv[2])) > NEAR_P);
        float inv = okA ? 1.0f / area : 0.0f;
        float* R = recs + t * REC;
        // w0 = edge(b,c)*inv : (X-bx)*(cy-by) - (Y-by)*(cx-bx)
        R[0] = (cy - by) * inv;
        R[1] = -(cx - bx) * inv;
        R[2] = (by * (cx - bx) - bx * (cy - by)) * inv;
        // w1 = edge(c,a)*inv
        R[3] = (ay - cy) * inv;
        R[4] = -(ax - cx) * inv;
        R[5] = (cy * (ax - cx) - cx * (ay - cy)) * inv;
        // w2 = edge(a,b)*inv
        R[6] = (by - ay) * inv;
        R[7] = -(bx - ax) * inv;
        R[8] = (ay * (bx - ax) - ax * (by - ay)) * inv;
        R[9]  = valid ? opacity[src] : 0.0f;
        R[10] = feature[src*3 + 0];
        R[11] = feature[src*3 + 1];
        R[12] = feature[src*3 + 2];
        R[13] = 0.0f; R[14] = 0.0f; R[15] = 0.0f;
        // conservative bbox: pixels with center inside triangle lie within
        // the vertex bbox. Invalid triangles -> empty bbox (culled).
        float mnx = fminf(ax, fminf(bx, cx)), mxx = fmaxf(ax, fmaxf(bx, cx));
        float mny = fminf(ay, fminf(by, cy)), mxy = fmaxf(ay, fmaxf(by, cy));
        if (valid) bbox[t] = make_float4(mnx, mny, mxx, mxy);
        else       bbox[t] = make_float4(1e30f, 1e30f, -1e30f, -1e30f);
    }
}

// 256 blocks x 64 threads: one 8x8 pixel tile per block (one wave).
// Chunked bbox cull + ballot-compaction into LDS, then composite survivors.
__global__ __launch_bounds__(64)
void composite_kernel(const float* __restrict__ recs,
                      const float4* __restrict__ bbox, int N,
                      const float* __restrict__ background,
                      float* __restrict__ out)
{
    __shared__ float s_rec[64 * REC];
    const int lane = threadIdx.x;
    const int tx = (int)blockIdx.x & 15;
    const int ty = (int)blockIdx.x >> 4;
    const int pxi = tx * 8 + (lane & 7);
    const int pyi = ty * 8 + (lane >> 3);
    const float X = (float)pxi + 0.5f;
    const float Y = (float)pyi + 0.5f;
    const float xlo = tx * 8 + 0.5f, xhi = tx * 8 + 7.5f;
    const float ylo = ty * 8 + 0.5f, yhi = ty * 8 + 7.5f;

    float T = 1.0f, cr = 0.0f, cg = 0.0f, cb = 0.0f;

    for (int base = 0; base < N; base += 64) {
        const int i = base + lane;
        bool pred = false;
        if (i < N) {
            float4 bb = bbox[i];  // (minx, miny, maxx, maxy)
            pred = (bb.x <= xhi) && (bb.z >= xlo) &&
                   (bb.y <= yhi) && (bb.w >= ylo);
        }
        unsigned long long m = __ballot(pred);
        int cnt = __popcll(m);
        if (cnt == 0) continue;
        int pos = __popcll(m & ((1ull << lane) - 1ull));
        __syncthreads();
        if (pred) {
            const float4* s4 = (const float4*)(recs + i * REC);
            float4* d4 = (float4*)(s_rec + pos * REC);
            d4[0] = s4[0]; d4[1] = s4[1]; d4[2] = s4[2]; d4[3] = s4[3];
        }
        __syncthreads();

        for (int j = 0; j < cnt; ++j) {
            const float4* R4 = (const float4*)(s_rec + j * REC);
            float4 r0 = R4[0], r1 = R4[1], r2 = R4[2], r3 = R4[3];
            float w0 = fmaf(r0.x, X, fmaf(r0.y, Y, r0.z));
            float w1 = fmaf(r0.w, X, fmaf(r1.x, Y, r1.y));
            float w2 = fmaf(r1.z, X, fmaf(r1.w, Y, r2.x));
            float mn = fminf(w0, fminf(w1, w2));
            float cov = fminf(fmaxf(3.0f * mn, 0.0f), 1.0f);
            if (cov > 0.0f) {
                float alpha = fminf(r2.y * cov, 0.999f);
                float w = T * alpha;
                cr = fmaf(w, r2.z, cr);
                cg = fmaf(w, r2.w, cg);
                cb = fmaf(w, r3.x, cb);
                T *= (1.0f - alpha);
            }
        }
    }

    const int pix = pyi * HW + pxi;
    out[pix]            = fmaf(T, background[0], cr);
    out[HWHW + pix]     = fmaf(T, background[1], cg);
    out[2 * HWHW + pix] = fmaf(T, background[2], cb);
}

} // namespace

extern "C" void kernel_launch(void* const* d_in, const int* in_sizes, int n_in,
                              void* d_out, int out_size, void* d_ws, size_t ws_size,
                              hipStream_t stream)
{
    const float* vertex   = (const float*)d_in[0];
    // d_in[1] = center2D (unused by reference output)
    const float* opacity  = (const float*)d_in[2];
    const float* feature  = (const float*)d_in[3];
    const float* vm       = (const float*)d_in[4];
    const float* pm       = (const float*)d_in[5];
    // d_in[6] = campos (unused)
    const float* bg       = (const float*)d_in[7];

    const int N = in_sizes[0] / 9;   // 1024

    float*  out  = (float*)d_out;                    // [3*128*128] feature, then [N] radii
    float*  recs = (float*)d_ws;                     // SORT_N*REC floats (64 KB)
    float4* bbox = (float4*)(recs + SORT_N * REC);   // SORT_N float4 (16 KB)

    prep_sort_kernel<<<1, SORT_N, 0, stream>>>(vertex, opacity, feature, vm, pm,
                                               recs, bbox, out + 3 * HWHW, N);
    composite_kernel<<<256, 64, 0, stream>>>(recs, bbox, N, bg, out);
}

// Round 4
// 9.703 us; speedup vs baseline: 11.8707x; 4.3512x over previous
//
#include <hip/hip_runtime.h>
#include <math.h>

// NOTE ON THE ALGORITHM (do not "fix" this back to a real rasterizer):
// The reference's edge-function sign convention gives the identity
//   e_bc + e_ca + e_ab == -area   (linear terms cancel; constant = e_bc(a))
// so w0 + w1 + w2 == -1 for every pixel/triangle, min(w) <= -1/3,
// cov = clamp(3*min(w), 0, 1) == 0, alpha == 0, T == 1. Therefore
// out_feature == background broadcast EXACTLY, and only radii are
// non-trivial. Rounds 1-2 (full faithful rasterization) passed with
// absmax = 0.0 exactly, confirming the composite contributes nothing.

namespace {

constexpr int   HW     = 128;
constexpr int   HWHW   = HW * HW;
constexpr float NEAR_P = 0.2f;
constexpr float EPS_P  = 1e-8f;
constexpr int   IMG4       = 3 * HWHW / 4;   // 12288 float4 stores
constexpr int   IMG_BLOCKS = IMG4 / 256;     // 48 blocks

__global__ __launch_bounds__(256)
void final_kernel(const float* __restrict__ vertex,   // N*9
                  const float* __restrict__ vm,       // 16
                  const float* __restrict__ pm,       // 16
                  const float* __restrict__ bg,       // 3
                  float* __restrict__ out,            // 3*HWHW + N
                  int N)
{
    const int bid = (int)blockIdx.x;
    const int tid = (int)threadIdx.x;

    if (bid < IMG_BLOCKS) {
        // image = background broadcast (see proof above). One float4/thread;
        // 4096 float4 per channel, so each float4 is within one channel.
        int j = bid * 256 + tid;                 // 0 .. 12287
        float c = bg[j >> 12];                   // channel = (j*4) / 16384
        ((float4*)out)[j] = make_float4(c, c, c, c);
        return;
    }

    // ---- radii path: one triangle per thread ----
    int i = (bid - IMG_BLOCKS) * 256 + tid;
    if (i >= N) return;

    const float* v = vertex + i * 9;
    float px[3], py[3], zv[3];
    #pragma unroll
    for (int k = 0; k < 3; ++k) {
        float x = v[k*3+0], y = v[k*3+1], z = v[k*3+2];
        zv[k] = x*vm[2] + y*vm[6] + z*vm[10] + vm[14];
        float h0 = x*pm[0] + y*pm[4] + z*pm[8]  + pm[12];
        float h1 = x*pm[1] + y*pm[5] + z*pm[9]  + pm[13];
        float h3 = x*pm[3] + y*pm[7] + z*pm[11] + pm[15];
        float w  = h3 + 1e-7f;
        px[k] = ((h0 / w + 1.0f) * (float)HW - 1.0f) * 0.5f;
        py[k] = ((h1 / w + 1.0f) * (float)HW - 1.0f) * 0.5f;
    }
    float area = (px[1]-px[0])*(py[2]-py[0]) - (py[1]-py[0])*(px[2]-px[0]);
    bool valid = (fabsf(area) > EPS_P) &&
                 (fminf(zv[0], fminf(zv[1], zv[2])) > NEAR_P);
    float cx = (px[0] + px[1] + px[2]) / 3.0f;
    float cy = (py[0] + py[1] + py[2]) / 3.0f;
    float r = 0.0f;
    #pragma unroll
    for (int k = 0; k < 3; ++k) {
        float dx = px[k] - cx, dy = py[k] - cy;
        r = fmaxf(r, sqrtf(dx*dx + dy*dy));
    }
    out[3*HWHW + i] = valid ? ceilf(r) : 0.0f;
}

} // namespace

extern "C" void kernel_launch(void* const* d_in, const int* in_sizes, int n_in,
                              void* d_out, int out_size, void* d_ws, size_t ws_size,
                              hipStream_t stream)
{
    const float* vertex = (const float*)d_in[0];
    // d_in[1] = center2D (unused), d_in[2] = opacity (dead: alpha==0),
    // d_in[3] = feature (dead: weights==0), d_in[6] = campos (unused)
    const float* vm     = (const float*)d_in[4];
    const float* pm     = (const float*)d_in[5];
    const float* bg     = (const float*)d_in[7];

    const int N = in_sizes[0] / 9;   // 1024
    float* out = (float*)d_out;      // [3*128*128] feature, then [N] radii

    const int radii_blocks = (N + 255) / 256;
    final_kernel<<<IMG_BLOCKS + radii_blocks, 256, 0, stream>>>(
        vertex, vm, pm, bg, out, N);
}